// Round 1
// baseline (213.840 us; speedup 1.0000x reference)
//
#include <hip/hip_runtime.h>

#define IN_NUM 1152
#define OUT_NUM 10
#define OUT_DIM 16
#define IN_DIM 8
#define NB 256                       // batch
#define K9216 (IN_DIM * IN_NUM)      // 9216
#define ISPLIT 12
#define IRANGE (IN_NUM / ISPLIT)     // 96
#define ICH 32

// workspace float offsets
#define OFF_BIJ 0
#define OFF_C (OFF_BIJ + IN_NUM * OUT_NUM)            // 11520
#define OFF_SPART (OFF_C + IN_NUM * OUT_NUM)          // 23040
#define SPART_SZ (ISPLIT * OUT_NUM * OUT_DIM * NB)    // 491520
#define OFF_V (OFF_SPART + SPART_SZ)                  // 514560
#define OFF_M (OFF_V + OUT_NUM * OUT_DIM * NB)        // 555520
// total = 555520 + 10*16*9216 = 2030080 floats = 8.12 MB

// c[i,j] = softmax_j(b_ij[i,:])
__global__ void k_softmax(const float* __restrict__ bij, float* __restrict__ cmat) {
    int i = blockIdx.x * 256 + threadIdx.x;
    if (i >= IN_NUM) return;
    float r[OUT_NUM];
    float m = -1e30f;
#pragma unroll
    for (int j = 0; j < OUT_NUM; ++j) { r[j] = bij[i * OUT_NUM + j]; m = fmaxf(m, r[j]); }
    float s = 0.f;
#pragma unroll
    for (int j = 0; j < OUT_NUM; ++j) { r[j] = __expf(r[j] - m); s += r[j]; }
    float inv = 1.0f / s;
#pragma unroll
    for (int j = 0; j < OUT_NUM; ++j) cmat[i * OUT_NUM + j] = r[j] * inv;
}

// s_part[isp][j][d][b] = sum_{i in isp-range} sum_c c[i,j]*W[i,j,d,c]*x[b,c,i]
// grid (ISPLIT, 4 b-tiles, OUT_NUM), block 256 = 64 bb x 4 dg
__global__ void k_s(const float* __restrict__ x, const float* __restrict__ W,
                    const float* __restrict__ cmat, float* __restrict__ spart) {
    __shared__ float xt[ICH][65];   // [kk][bb], padded: conflict-free both phases
    __shared__ float at[ICH][16];   // [kk][d] = c[i,j]*W[i,j,d,c]
    int t = threadIdx.x;
    int bb = t & 63, dg = t >> 6;
    int isp = blockIdx.x, bt = blockIdx.y, j = blockIdx.z;
    int b0 = bt * 64;
    int r8 = t >> 3;   // 0..31
    int l8 = t & 7;    // 0..7
    float acc[4] = {0.f, 0.f, 0.f, 0.f};

    for (int c = 0; c < IN_DIM; ++c) {
        for (int ch = 0; ch < IRANGE / ICH; ++ch) {
            int i0 = isp * IRANGE + ch * ICH;
            __syncthreads();   // protect previous tile's reads
            // stage x tile: rows bb2, 32 consecutive i (coalesced float4)
#pragma unroll
            for (int q = 0; q < 2; ++q) {
                int bb2 = r8 + q * 32;
                float4 xv = *reinterpret_cast<const float4*>(
                    &x[(size_t)(b0 + bb2) * K9216 + c * IN_NUM + i0 + l8 * 4]);
                xt[l8 * 4 + 0][bb2] = xv.x;
                xt[l8 * 4 + 1][bb2] = xv.y;
                xt[l8 * 4 + 2][bb2] = xv.z;
                xt[l8 * 4 + 3][bb2] = xv.w;
            }
            // stage A tile: at[kk][d] = c[i0+kk, j] * W[i0+kk, j, d, c]
            {
                int i_ = i0 + r8;
                float cj = cmat[i_ * OUT_NUM + j];
                const float* wp = &W[(size_t)i_ * (OUT_NUM * OUT_DIM * IN_DIM) + j * (OUT_DIM * IN_DIM) + c];
                at[r8][l8 * 2 + 0] = cj * wp[(l8 * 2 + 0) * IN_DIM];
                at[r8][l8 * 2 + 1] = cj * wp[(l8 * 2 + 1) * IN_DIM];
            }
            __syncthreads();
#pragma unroll
            for (int kk = 0; kk < ICH; ++kk) {
                float xv = xt[kk][bb];
                float4 a4 = *reinterpret_cast<const float4*>(&at[kk][dg * 4]);
                acc[0] += a4.x * xv;
                acc[1] += a4.y * xv;
                acc[2] += a4.z * xv;
                acc[3] += a4.w * xv;
            }
        }
    }
#pragma unroll
    for (int dd = 0; dd < 4; ++dd)
        spart[(size_t)((isp * OUT_NUM + j) * OUT_DIM + dg * 4 + dd) * NB + b0 + bb] = acc[dd];
}

// reduce partials over isp, apply squash; write v (iters 0,1) or transposed output (iter 2)
// grid (OUT_NUM), block NB
__global__ void k_squash(const float* __restrict__ spart, float* __restrict__ v,
                         float* __restrict__ out, int write_out) {
    int j = blockIdx.x;
    int b = threadIdx.x;
    float s[OUT_DIM];
#pragma unroll
    for (int d = 0; d < OUT_DIM; ++d) s[d] = 0.f;
    for (int isp = 0; isp < ISPLIT; ++isp) {
#pragma unroll
        for (int d = 0; d < OUT_DIM; ++d)
            s[d] += spart[(size_t)((isp * OUT_NUM + j) * OUT_DIM + d) * NB + b];
    }
    float sq = 0.f;
#pragma unroll
    for (int d = 0; d < OUT_DIM; ++d) sq += s[d] * s[d];
    float coef = sq / ((1.f + sq) * sqrtf(sq));
    if (write_out) {
#pragma unroll
        for (int d = 0; d < OUT_DIM; ++d)
            out[(size_t)b * (OUT_NUM * OUT_DIM) + j * OUT_DIM + d] = s[d] * coef;
    } else {
#pragma unroll
        for (int d = 0; d < OUT_DIM; ++d)
            v[(size_t)(j * OUT_DIM + d) * NB + b] = s[d] * coef;
    }
}

// M[j][d][k] = sum_b v[j,b,d] * x[b,k]   (k = c*IN_NUM + i)
// grid (K9216/64, OUT_NUM/2), block 256 = 64 kk x 4 dg; 2 j's per block
__global__ void k_M(const float* __restrict__ x, const float* __restrict__ v,
                    float* __restrict__ M) {
    __shared__ float vs[2 * NB * 20];   // [jj][b][d] rows padded to 20 (16B-aligned f4 reads)
    int t = threadIdx.x;
    int k0 = blockIdx.x * 64;
    int j0 = blockIdx.y * 2;
    // stage v for 2 output capsules, transposed to [b][d]
    for (int n = 0; n < 32; ++n) {
        int e = t + n * 256;               // 0..8191
        int jj = e >> 12, rem = e & 4095;
        int d = rem >> 8, b = rem & 255;
        vs[(jj * NB + b) * 20 + d] = v[(size_t)(j0 + jj) * (OUT_DIM * NB) + d * NB + b];
    }
    __syncthreads();
    int kk = t & 63, dg = t >> 6;
    int k = k0 + kk;
    float acc[8];
#pragma unroll
    for (int q = 0; q < 8; ++q) acc[q] = 0.f;
#pragma unroll 4
    for (int b = 0; b < NB; ++b) {
        float xv = x[(size_t)b * K9216 + k];
        float4 v0 = *reinterpret_cast<const float4*>(&vs[(0 * NB + b) * 20 + dg * 4]);
        float4 v1 = *reinterpret_cast<const float4*>(&vs[(1 * NB + b) * 20 + dg * 4]);
        acc[0] += v0.x * xv; acc[1] += v0.y * xv; acc[2] += v0.z * xv; acc[3] += v0.w * xv;
        acc[4] += v1.x * xv; acc[5] += v1.y * xv; acc[6] += v1.z * xv; acc[7] += v1.w * xv;
    }
#pragma unroll
    for (int jj = 0; jj < 2; ++jj)
#pragma unroll
        for (int dd = 0; dd < 4; ++dd)
            M[(size_t)((j0 + jj) * OUT_DIM + dg * 4 + dd) * K9216 + k] = acc[jj * 4 + dd];
}

// b_ij[i,j] += (1/NB) * sum_{dc} W[i,j,dc] * M[j,dc,i]
// grid (45), block 256 -> exactly 11520 threads
__global__ void k_bupd(const float* __restrict__ W, const float* __restrict__ M,
                       float* __restrict__ bij) {
    int tg = blockIdx.x * 256 + threadIdx.x;
    int j = tg / IN_NUM;    // i-minor: M reads coalesced
    int i = tg % IN_NUM;
    float acc = 0.f;
#pragma unroll 8
    for (int dc = 0; dc < OUT_DIM * IN_DIM; ++dc)
        acc += W[(size_t)i * (OUT_NUM * OUT_DIM * IN_DIM) + j * (OUT_DIM * IN_DIM) + dc]
             * M[(size_t)j * (OUT_DIM * K9216) + dc * IN_NUM + i];
    bij[i * OUT_NUM + j] += acc * (1.0f / NB);
}

extern "C" void kernel_launch(void* const* d_in, const int* in_sizes, int n_in,
                              void* d_out, int out_size, void* d_ws, size_t ws_size,
                              hipStream_t stream) {
    const float* x = (const float*)d_in[0];   // [256][8][1152]
    const float* W = (const float*)d_in[1];   // [1152][10][16][8]
    float* out = (float*)d_out;               // [256][10][16][1]
    float* ws = (float*)d_ws;

    float* bij = ws + OFF_BIJ;
    float* cmat = ws + OFF_C;
    float* spart = ws + OFF_SPART;
    float* v = ws + OFF_V;
    float* M = ws + OFF_M;

    hipMemsetAsync(bij, 0, IN_NUM * OUT_NUM * sizeof(float), stream);

    for (int it = 0; it < 3; ++it) {
        k_softmax<<<dim3(5), dim3(256), 0, stream>>>(bij, cmat);
        k_s<<<dim3(ISPLIT, 4, OUT_NUM), dim3(256), 0, stream>>>(x, W, cmat, spart);
        k_squash<<<dim3(OUT_NUM), dim3(NB), 0, stream>>>(spart, v, out, it == 2 ? 1 : 0);
        if (it < 2) {
            k_M<<<dim3(K9216 / 64, OUT_NUM / 2), dim3(256), 0, stream>>>(x, v, M);
            k_bupd<<<dim3(45), dim3(256), 0, stream>>>(W, M, bij);
        }
    }
}

// Round 2
// 139.301 us; speedup vs baseline: 1.5351x; 1.5351x over previous
//
#include <hip/hip_runtime.h>

#define IN_NUM 1152
#define OUT_NUM 10
#define OUT_DIM 16
#define IN_DIM 8
#define NB 256
#define KTOT 9216
#define ISPLIT 96
#define KCH (KTOT / ISPLIT)   // 96

// workspace float offsets
#define OFF_A2 0
#define SZ_A2 (OUT_NUM * KTOT * OUT_DIM)            // 1,474,560
#define OFF_SPART (OFF_A2 + SZ_A2)
#define SZ_SPART (ISPLIT * OUT_NUM * OUT_DIM * NB)  // 3,932,160
#define OFF_VT (OFF_SPART + SZ_SPART)
#define SZ_VT (NB * OUT_NUM * OUT_DIM)              // 40,960
#define OFF_BP (OFF_VT + SZ_VT)
#define SZ_BP (2 * IN_DIM * IN_NUM * OUT_NUM)       // 184,320
#define OFF_WT (OFF_BP + SZ_BP)
#define SZ_WT (OUT_NUM * OUT_DIM * IN_DIM * IN_NUM) // 1,474,560
// total ~28.4 MB

// ---- one-time: W[i][j][d][c] -> Wt[j][d][c][i] ----
__global__ void k_wt(const float* __restrict__ W, float* __restrict__ Wt) {
    __shared__ float lds[64][129];
    int t = threadIdx.x;
    int it = blockIdx.x, j = blockIdx.y;
    int i0 = it * 64;
    int r0 = t >> 5, c4 = t & 31;
#pragma unroll
    for (int rr = 0; rr < 8; ++rr) {
        int r = rr * 8 + r0;
        float4 w4 = *reinterpret_cast<const float4*>(
            &W[(size_t)(i0 + r) * 1280 + j * 128 + c4 * 4]);
        lds[r][c4 * 4 + 0] = w4.x; lds[r][c4 * 4 + 1] = w4.y;
        lds[r][c4 * 4 + 2] = w4.z; lds[r][c4 * 4 + 3] = w4.w;
    }
    __syncthreads();
    int dcq = t >> 6, ii = t & 63;
    for (int rr = 0; rr < 32; ++rr) {
        int dc = rr * 4 + dcq;
        Wt[(size_t)(j * 128 + dc) * IN_NUM + i0 + ii] = lds[ii][dc];
    }
}

// ---- per-iter: softmax(b_ij) fused with A2[j][k][d] = c[i,j]*W[i,j,d,c], k=c*1152+i ----
__global__ void k_prepA(const float* __restrict__ W, const float* __restrict__ bp,
                        float* __restrict__ A2) {
    __shared__ float lds[64][129];
    __shared__ float ldc[64];
    int t = threadIdx.x;
    int it = blockIdx.x, j = blockIdx.y;
    int i0 = it * 64;
    // stage W rows
    int r0 = t >> 5, c4 = t & 31;
#pragma unroll
    for (int rr = 0; rr < 8; ++rr) {
        int r = rr * 8 + r0;
        float4 w4 = *reinterpret_cast<const float4*>(
            &W[(size_t)(i0 + r) * 1280 + j * 128 + c4 * 4]);
        lds[r][c4 * 4 + 0] = w4.x; lds[r][c4 * 4 + 1] = w4.y;
        lds[r][c4 * 4 + 2] = w4.z; lds[r][c4 * 4 + 3] = w4.w;
    }
    // softmax over j for this block's 64 i's (only this block's j coefficient kept)
    if (t < 64) {
        int i = i0 + t;
        float bt[OUT_NUM];
#pragma unroll
        for (int jp = 0; jp < OUT_NUM; ++jp) bt[jp] = 0.f;
        for (int row = 0; row < 16; ++row) {   // (bh,c) rows
            const float* p = &bp[((size_t)row * IN_NUM + i) * OUT_NUM];
#pragma unroll
            for (int jp = 0; jp < OUT_NUM; ++jp) bt[jp] += p[jp];
        }
        float m = -1e30f;
#pragma unroll
        for (int jp = 0; jp < OUT_NUM; ++jp) { bt[jp] *= (1.f / NB); m = fmaxf(m, bt[jp]); }
        float s = 0.f;
#pragma unroll
        for (int jp = 0; jp < OUT_NUM; ++jp) { bt[jp] = __expf(bt[jp] - m); s += bt[jp]; }
        ldc[t] = bt[j] / s;
    }
    __syncthreads();
    // write A2: thread = ii*4 + dq  (coalesced 16B/lane stores)
    int dq = t & 3, ii = t >> 2;
    float cv = ldc[ii];
    for (int c = 0; c < IN_DIM; ++c) {
        float4 a;
        a.x = cv * lds[ii][(dq * 4 + 0) * 8 + c];
        a.y = cv * lds[ii][(dq * 4 + 1) * 8 + c];
        a.z = cv * lds[ii][(dq * 4 + 2) * 8 + c];
        a.w = cv * lds[ii][(dq * 4 + 3) * 8 + c];
        *reinterpret_cast<float4*>(
            &A2[((size_t)j * KTOT + c * IN_NUM + i0 + ii) * OUT_DIM + dq * 4]) = a;
    }
}

// ---- s-GEMM: spart[isp][j][d][b] = sum_{k in chunk} A2[j][k][d] * x[b][k] ----
// A2 loads are wave-uniform -> s_load; x direct from global (L2). No LDS.
__global__ __launch_bounds__(256) void k_s(const float* __restrict__ x,
                                           const float* __restrict__ A2,
                                           float* __restrict__ spart) {
    int bid = blockIdx.x;                 // XCD swizzle: co-locate the 10 j's per isp
    int g8 = bid / 80, r = bid % 80;
    int j = r >> 3, isp = g8 * 8 + (r & 7);
    int b = threadIdx.x;
    int k0 = isp * KCH;
    const float* Aj = A2 + ((size_t)j * KTOT + k0) * OUT_DIM;
    const float* xb = x + (size_t)b * KTOT + k0;
    float acc[16];
#pragma unroll
    for (int d = 0; d < 16; ++d) acc[d] = 0.f;
#pragma unroll 2
    for (int g = 0; g < KCH / 4; ++g) {
        float4 xv = *reinterpret_cast<const float4*>(&xb[g * 4]);
        const float* Ag = Aj + g * 64;
#pragma unroll
        for (int d = 0; d < 16; ++d) acc[d] += Ag[d] * xv.x;
#pragma unroll
        for (int d = 0; d < 16; ++d) acc[d] += Ag[16 + d] * xv.y;
#pragma unroll
        for (int d = 0; d < 16; ++d) acc[d] += Ag[32 + d] * xv.z;
#pragma unroll
        for (int d = 0; d < 16; ++d) acc[d] += Ag[48 + d] * xv.w;
    }
    float* sp = spart + (size_t)(isp * OUT_NUM + j) * OUT_DIM * NB + b;
#pragma unroll
    for (int d = 0; d < 16; ++d) sp[d * NB] = acc[d];
}

// ---- reduce spart over isp, squash, write vt[b][j][d] (or final out, same layout) ----
__global__ void k_squash(const float* __restrict__ spart, float* __restrict__ dst) {
    __shared__ float red[8][32][17];
    __shared__ float nrm[32][9];
    __shared__ float cf[32];
    int j = blockIdx.x, bt = blockIdx.y;
    int t = threadIdx.x;
    int ie = t >> 5, bb = t & 31;
    int b = bt * 32 + bb;
    float acc[16];
#pragma unroll
    for (int d = 0; d < 16; ++d) acc[d] = 0.f;
    for (int q = 0; q < ISPLIT / 8; ++q) {
        int isp = ie * (ISPLIT / 8) + q;
        const float* sp = spart + (size_t)(isp * OUT_NUM + j) * OUT_DIM * NB + b;
#pragma unroll
        for (int d = 0; d < 16; ++d) acc[d] += sp[d * NB];
    }
#pragma unroll
    for (int d = 0; d < 16; ++d) red[ie][bb][d] = acc[d];
    __syncthreads();
    int bb2 = t >> 3, dp = t & 7;
    float s0 = 0.f, s1 = 0.f;
#pragma unroll
    for (int e = 0; e < 8; ++e) { s0 += red[e][bb2][dp * 2]; s1 += red[e][bb2][dp * 2 + 1]; }
    nrm[bb2][dp] = s0 * s0 + s1 * s1;
    __syncthreads();
    if (t < 32) {
        float q = 0.f;
#pragma unroll
        for (int d = 0; d < 8; ++d) q += nrm[t][d];
        cf[t] = q / ((1.f + q) * sqrtf(q));
    }
    __syncthreads();
    float c = cf[bb2];
    float* o = dst + (size_t)(bt * 32 + bb2) * (OUT_NUM * OUT_DIM) + j * OUT_DIM + dp * 2;
    o[0] = s0 * c;
    o[1] = s1 * c;
}

// ---- fused M-GEMM + b-update: bp[bh][c][i][j] += sum_d Wt[j][d][c][i] * sum_b vt[b][j][d]*x[b][k] ----
// one wave per block; vt loads wave-uniform -> s_load. No LDS, no atomics.
__global__ __launch_bounds__(64) void k_Mb(const float* __restrict__ x,
                                           const float* __restrict__ vt,
                                           const float* __restrict__ Wt,
                                           float* __restrict__ bp) {
    int bid = blockIdx.x;                 // swizzle: co-locate the 20 (j,bh) per kt
    int g8 = bid / 160, r = bid % 160;
    int jb = r >> 3;
    int kt = g8 * 8 + (r & 7);
    int j = jb >> 1, bh = jb & 1;
    int lane = threadIdx.x;
    int k = kt * 64 + lane;
    int c = k / IN_NUM;
    int i = k - c * IN_NUM;
    const float* xk = x + k;
    const float* vj = vt + j * OUT_DIM;
    float acc[16];
#pragma unroll
    for (int d = 0; d < 16; ++d) acc[d] = 0.f;
    int b0 = bh * 128;
#pragma unroll 4
    for (int b = b0; b < b0 + 128; ++b) {
        float xv = xk[(size_t)b * KTOT];
        const float* vb = vj + (size_t)b * (OUT_NUM * OUT_DIM);  // uniform
#pragma unroll
        for (int d = 0; d < 16; ++d) acc[d] += vb[d] * xv;
    }
    float bs = 0.f;
#pragma unroll
    for (int d = 0; d < 16; ++d)
        bs += acc[d] * Wt[((size_t)(j * OUT_DIM + d) * IN_DIM + c) * IN_NUM + i];
    bp[((size_t)(bh * IN_DIM + c) * IN_NUM + i) * OUT_NUM + j] += bs;
}

extern "C" void kernel_launch(void* const* d_in, const int* in_sizes, int n_in,
                              void* d_out, int out_size, void* d_ws, size_t ws_size,
                              hipStream_t stream) {
    const float* x = (const float*)d_in[0];   // [256][8][1152]
    const float* W = (const float*)d_in[1];   // [1152][10][16][8]
    float* out = (float*)d_out;               // [256][10][16]
    float* ws = (float*)d_ws;

    float* A2 = ws + OFF_A2;
    float* spart = ws + OFF_SPART;
    float* vt = ws + OFF_VT;
    float* bp = ws + OFF_BP;
    float* Wt = ws + OFF_WT;

    hipMemsetAsync(bp, 0, SZ_BP * sizeof(float), stream);
    k_wt<<<dim3(18, 10), dim3(256), 0, stream>>>(W, Wt);

    for (int it = 0; it < 3; ++it) {
        k_prepA<<<dim3(18, 10), dim3(256), 0, stream>>>(W, bp, A2);
        k_s<<<dim3(ISPLIT * 10), dim3(256), 0, stream>>>(x, A2, spart);
        k_squash<<<dim3(10, 8), dim3(256), 0, stream>>>(spart, it == 2 ? out : vt);
        if (it < 2)
            k_Mb<<<dim3(2880), dim3(64), 0, stream>>>(x, vt, Wt, bp);
    }
}